// Round 4
// baseline (204.597 us; speedup 1.0000x reference)
//
#include <hip/hip_runtime.h>
#include <stdint.h>

#define M_DIM 8192
#define K_DIM 4096
#define N_DIM 4096

#define BM 128
#define BN 256
#define BKB 64    // K-bytes per tile (i8), 64-B rows
#define NT 64     // K_DIM / BKB

typedef __attribute__((ext_vector_type(4))) int i32x4;
typedef unsigned char u8;
typedef unsigned int u32;

// ---------------- prepass: quantize x to per-row i8, w to sign i8 ----------------

__device__ __forceinline__ signed char sgn8(float f) {
  return (f > 0.0f) ? (signed char)1 : ((f < 0.0f) ? (signed char)-1 : (signed char)0);
}

// one block per row: rowmax -> scale -> quantize 4096 floats to i8
__global__ __launch_bounds__(256) void cvt_x_i8(const float* __restrict__ x,
                                                signed char* __restrict__ xq,
                                                float* __restrict__ scales) {
  const int row = blockIdx.x;
  const float4* xr = (const float4*)(x + (size_t)row * K_DIM);
  const int tid = threadIdx.x;

  float4 v[4];
#pragma unroll
  for (int k = 0; k < 4; ++k) v[k] = xr[tid * 4 + k];

  float m = 0.0f;
#pragma unroll
  for (int k = 0; k < 4; ++k) {
    m = fmaxf(m, fmaxf(fmaxf(fabsf(v[k].x), fabsf(v[k].y)),
                       fmaxf(fabsf(v[k].z), fabsf(v[k].w))));
  }
#pragma unroll
  for (int off = 32; off; off >>= 1) m = fmaxf(m, __shfl_xor(m, off));

  __shared__ float wmax[4];
  if ((tid & 63) == 0) wmax[tid >> 6] = m;
  __syncthreads();
  m = fmaxf(fmaxf(wmax[0], wmax[1]), fmaxf(wmax[2], wmax[3]));
  m = fmaxf(m, 1e-30f);

  const float inv = 127.0f / m;
  if (tid == 0) scales[row] = m / 127.0f;

  signed char q[16] __attribute__((aligned(16)));
#pragma unroll
  for (int k = 0; k < 4; ++k) {
    const float* p = (const float*)&v[k];
#pragma unroll
    for (int j = 0; j < 4; ++j) {
      float t = fminf(fmaxf(p[j] * inv, -127.0f), 127.0f);
      q[k * 4 + j] = (signed char)__float2int_rn(t);
    }
  }
  *(int4*)(xq + (size_t)row * K_DIM + tid * 16) = *(const int4*)q;
}

__global__ __launch_bounds__(256) void cvt_w_i8(const float4* __restrict__ w,
                                                int4* __restrict__ wq) {
  const int i = blockIdx.x * blockDim.x + threadIdx.x;  // 16 floats / thread
  signed char q[16] __attribute__((aligned(16)));
#pragma unroll
  for (int k = 0; k < 4; ++k) {
    float4 v = w[i * 4 + k];
    q[k * 4 + 0] = sgn8(v.x);
    q[k * 4 + 1] = sgn8(v.y);
    q[k * 4 + 2] = sgn8(v.z);
    q[k * 4 + 3] = sgn8(v.w);
  }
  wq[i] = *(const int4*)q;
}

// ---------------- GEMM ----------------

// async global->LDS, 16 B/lane. LDS dest is the WAVE-UNIFORM base (HW adds lane*16);
// global src is per-lane (pre-swizzled so the linear LDS write lands swizzled).
__device__ __forceinline__ void load16_to_lds(const u8* g, const u8* l) {
  auto gp = reinterpret_cast<const __attribute__((address_space(1))) void*>(
      reinterpret_cast<uintptr_t>(g));
  auto lp = reinterpret_cast<__attribute__((address_space(3))) void*>(
      static_cast<uint32_t>(reinterpret_cast<uintptr_t>(l)));
  __builtin_amdgcn_global_load_lds(gp, lp, 16, 0, 0);
}

// 128x256 i8 GEMM, 2 blocks/CU: C = s_row * (Xq * Wq^T).
// 8 waves (2M x 4N), per-wave 64x64 out (acc 64 regs -> <=128 combined regs
// -> 16 waves/CU with __launch_bounds__(512,4)).
// LDS: triple-buffered [3][A 8KB | B 16KB] = 72 KiB (x2 blocks = 144 <= 160).
// Rows are 64 B = 4 x 16B chunks, stored at slot (chunk ^ (row&3)) via
// pre-swizzled global source + linear global_load_lds dest; ds_read applies
// the same XOR. Depth-2 prefetch: during tile t stage tile t+2 (3 issues/wave);
// gate at tile end = vmcnt(3) (leaves t+2's issues in flight), vmcnt(0) at t=62.
// One s_barrier per tile; per-subphase lgkmcnt(0)+sched_barrier(0) (rule #18).

__global__ __launch_bounds__(512, 4) void bingemm_kernel(const u8* __restrict__ A,
                                                         const u8* __restrict__ B,
                                                         const float* __restrict__ S,
                                                         float* __restrict__ C) {
  __shared__ __align__(16) u8 lds[3][24576];  // 72 KiB

  const int tid = threadIdx.x;
  const int wave = tid >> 6;
  const int lane = tid & 63;

  // XCD-bijective swizzle (1024 blocks % 8 XCDs == 0)
  const int orig = blockIdx.x;
  const int wgid = (orig & 7) * 128 + (orig >> 3);
  const int bm = wgid >> 4;  // 0..63
  const int bn = wgid & 15;  // 0..15

  const int wm = wave >> 2;  // 0..1 : wave's 64-row M slice
  const int wn = wave & 3;   // 0..3 : wave's 64-col N slice

  // ---- staging source (per-lane, pre-swizzled chunk) ----
  // One issue covers 1 KB/wave: lane l -> row wave*16 + (l>>2), chunk slot l&3,
  // which must hold source chunk (l&3) ^ (row&3).
  const int srow = wave * 16 + (lane >> 2);
  const int csw = (((lane & 3) ^ ((lane >> 2) & 3)) << 4);
  const u8* gA = A + (size_t)(bm * 128 + srow) * K_DIM + csw;
  const u8* gB0 = B + (size_t)(bn * 256 + srow) * K_DIM + csw;
  const u8* gB1 = gB0 + (size_t)128 * K_DIM;
  const int ldsw = wave * 1024;  // wave-uniform dest offset within a region

  // ---- ds_read fragment addressing (swizzled) ----
  // A frag mi: row = wm*64 + mi*16 + (lane&15), k-chunk lgrp=lane>>4, slot = lgrp^(row&3)
  const int lane15 = lane & 15;
  const int lgrp = lane >> 4;
  const int cswr = ((lgrp ^ (lane & 3)) << 4);
  const int offA0 = (wm * 64 + lane15) * 64 + cswr;
  const int offB0 = 8192 + (wn * 64 + lane15) * 64 + cswr;

  i32x4 acc[4][4];
  {
    const i32x4 z = {0, 0, 0, 0};
#pragma unroll
    for (int i = 0; i < 4; ++i)
#pragma unroll
      for (int j = 0; j < 4; ++j) acc[i][j] = z;
  }
  i32x4 af[4], bf[4];

#define STAGE_A(sp, T) load16_to_lds(gA + (size_t)(T) * BKB, (sp) + ldsw)
#define STAGE_B(sp, T)                                                   \
  do {                                                                   \
    load16_to_lds(gB0 + (size_t)(T) * BKB, (sp) + 8192 + ldsw);          \
    load16_to_lds(gB1 + (size_t)(T) * BKB, (sp) + 16384 + ldsw);         \
  } while (0)

  // ---- prologue: tiles 0,1 (3 issues each); leave tile-1's 3 in flight ----
  STAGE_A(&lds[0][0], 0);
  STAGE_B(&lds[0][0], 0);
  STAGE_A(&lds[1][0], 1);
  STAGE_B(&lds[1][0], 1);
  asm volatile("s_waitcnt vmcnt(3)" ::: "memory");
  __builtin_amdgcn_s_barrier();

  int cur = 0;
  for (int t = 0; t < NT; ++t) {
    const u8* bp = &lds[cur][0];
    u8* sp = &lds[cur == 0 ? 2 : cur - 1][0];  // (t+2) % 3
    const bool st = (t < NT - 2);

    // --- sub-phase A: A-frags + B-frags 0,1 ; stage A(t+2) ---
#pragma unroll
    for (int mi = 0; mi < 4; ++mi) af[mi] = *(const i32x4*)(bp + offA0 + mi * 1024);
    bf[0] = *(const i32x4*)(bp + offB0);
    bf[1] = *(const i32x4*)(bp + offB0 + 1024);
    if (st) STAGE_A(sp, t + 2);
    asm volatile("s_waitcnt lgkmcnt(0)" ::: "memory");
    __builtin_amdgcn_sched_barrier(0);
    __builtin_amdgcn_s_setprio(1);
#pragma unroll
    for (int ni = 0; ni < 2; ++ni)
#pragma unroll
      for (int mi = 0; mi < 4; ++mi)
        acc[mi][ni] = __builtin_amdgcn_mfma_i32_16x16x64_i8(af[mi], bf[ni], acc[mi][ni], 0, 0, 0);
    __builtin_amdgcn_s_setprio(0);

    // --- sub-phase B: B-frags 2,3 ; stage B(t+2) ---
    bf[2] = *(const i32x4*)(bp + offB0 + 2048);
    bf[3] = *(const i32x4*)(bp + offB0 + 3072);
    if (st) STAGE_B(sp, t + 2);
    asm volatile("s_waitcnt lgkmcnt(0)" ::: "memory");
    __builtin_amdgcn_sched_barrier(0);
    __builtin_amdgcn_s_setprio(1);
#pragma unroll
    for (int ni = 2; ni < 4; ++ni)
#pragma unroll
      for (int mi = 0; mi < 4; ++mi)
        acc[mi][ni] = __builtin_amdgcn_mfma_i32_16x16x64_i8(af[mi], bf[ni], acc[mi][ni], 0, 0, 0);
    __builtin_amdgcn_s_setprio(0);

    // --- tile gate: staging of t+1 (issued during t-1) must be landed ---
    if (t < NT - 2) {
      asm volatile("s_waitcnt vmcnt(3)" ::: "memory");
      __builtin_amdgcn_s_barrier();
    } else if (t == NT - 2) {
      asm volatile("s_waitcnt vmcnt(0)" ::: "memory");
      __builtin_amdgcn_s_barrier();
    }
    cur = (cur == 2) ? 0 : cur + 1;
  }

  // ---- epilogue: C/D layout col=lane&15, row=(lane>>4)*4+reg; dequant ----
  // Store drain overlaps the co-resident block's pipeline (2 blocks/CU).
  const int ccol = bn * 256 + wn * 64 + lane15;
  const int crow0 = bm * 128 + wm * 64 + (lgrp << 2);
#pragma unroll
  for (int mi = 0; mi < 4; ++mi) {
#pragma unroll
    for (int j = 0; j < 4; ++j) {
      const int row = crow0 + mi * 16 + j;
      const float s = S[row];
      float* cp = C + (size_t)row * N_DIM + ccol;
#pragma unroll
      for (int ni = 0; ni < 4; ++ni) cp[ni * 16] = s * (float)acc[mi][ni][j];
    }
  }
#undef STAGE_A
#undef STAGE_B
}

// Correctness fallback if d_ws is too small for the i8 staging buffers.
__global__ __launch_bounds__(256) void fallback_kernel(const float* __restrict__ x,
                                                       const float* __restrict__ w,
                                                       float* __restrict__ out) {
  const int col = blockIdx.x * 256 + threadIdx.x;
  const int row = blockIdx.y;
  const float* xr = x + (size_t)row * K_DIM;
  const float* wr = w + (size_t)col * K_DIM;
  float acc = 0.0f;
  for (int k = 0; k < K_DIM; k += 4) {
    float4 xv = *(const float4*)&xr[k];
    float4 wv = *(const float4*)&wr[k];
    acc += (wv.x > 0.0f ? xv.x : (wv.x < 0.0f ? -xv.x : 0.0f));
    acc += (wv.y > 0.0f ? xv.y : (wv.y < 0.0f ? -xv.y : 0.0f));
    acc += (wv.z > 0.0f ? xv.z : (wv.z < 0.0f ? -xv.z : 0.0f));
    acc += (wv.w > 0.0f ? xv.w : (wv.w < 0.0f ? -xv.w : 0.0f));
  }
  out[(size_t)row * N_DIM + col] = acc;
}

extern "C" void kernel_launch(void* const* d_in, const int* in_sizes, int n_in,
                              void* d_out, int out_size, void* d_ws, size_t ws_size,
                              hipStream_t stream) {
  const float* x = (const float*)d_in[0];  // (8192, 4096) fp32
  const float* w = (const float*)d_in[1];  // (4096, 4096) fp32
  float* out = (float*)d_out;              // (8192, 4096) fp32

  const size_t x_elems = (size_t)M_DIM * K_DIM;
  const size_t w_elems = (size_t)N_DIM * K_DIM;
  const size_t need = x_elems + w_elems + (size_t)M_DIM * sizeof(float);

  if (ws_size < need) {
    dim3 fgrid(N_DIM / 256, M_DIM);
    fallback_kernel<<<fgrid, 256, 0, stream>>>(x, w, out);
    return;
  }

  signed char* xq = (signed char*)d_ws;    // 32 MiB
  signed char* wq = xq + x_elems;          // 16 MiB
  float* scales = (float*)(wq + w_elems);  // 32 KiB

  cvt_x_i8<<<M_DIM, 256, 0, stream>>>(x, xq, scales);
  cvt_w_i8<<<(int)(w_elems / 16 / 256), 256, 0, stream>>>((const float4*)w, (int4*)wq);

  bingemm_kernel<<<(M_DIM / BM) * (N_DIM / BN), 512, 0, stream>>>(
      (const u8*)xq, (const u8*)wq, scales, out);
}

// Round 5
// 172.719 us; speedup vs baseline: 1.1846x; 1.1846x over previous
//
#include <hip/hip_runtime.h>
#include <stdint.h>

#define M_DIM 8192
#define K_DIM 4096
#define N_DIM 4096

#define BM 256
#define BN 256
#define BKB 128   // K-bytes (=elements) per tile, i8
#define NTILES 32 // K_DIM / BKB
#define NITER 16  // NTILES / 2

typedef __attribute__((ext_vector_type(4))) int i32x4;
typedef unsigned char u8;
typedef unsigned int u32;

// ---------------- prepass: quantize x to per-row i8, w to sign i8 ----------------

__device__ __forceinline__ signed char sgn8(float f) {
  return (f > 0.0f) ? (signed char)1 : ((f < 0.0f) ? (signed char)-1 : (signed char)0);
}

// one block per row: rowmax -> scale -> quantize 4096 floats to i8
__global__ __launch_bounds__(256) void cvt_x_i8(const float* __restrict__ x,
                                                signed char* __restrict__ xq,
                                                float* __restrict__ scales) {
  const int row = blockIdx.x;
  const float4* xr = (const float4*)(x + (size_t)row * K_DIM);
  const int tid = threadIdx.x;

  float4 v[4];
#pragma unroll
  for (int k = 0; k < 4; ++k) v[k] = xr[tid * 4 + k];

  float m = 0.0f;
#pragma unroll
  for (int k = 0; k < 4; ++k) {
    m = fmaxf(m, fmaxf(fmaxf(fabsf(v[k].x), fabsf(v[k].y)),
                       fmaxf(fabsf(v[k].z), fabsf(v[k].w))));
  }
#pragma unroll
  for (int off = 32; off; off >>= 1) m = fmaxf(m, __shfl_xor(m, off));

  __shared__ float wmax[4];
  if ((tid & 63) == 0) wmax[tid >> 6] = m;
  __syncthreads();
  m = fmaxf(fmaxf(wmax[0], wmax[1]), fmaxf(wmax[2], wmax[3]));
  m = fmaxf(m, 1e-30f);

  const float inv = 127.0f / m;
  if (tid == 0) scales[row] = m / 127.0f;

  signed char q[16] __attribute__((aligned(16)));
#pragma unroll
  for (int k = 0; k < 4; ++k) {
    const float* p = (const float*)&v[k];
#pragma unroll
    for (int j = 0; j < 4; ++j) {
      float t = fminf(fmaxf(p[j] * inv, -127.0f), 127.0f);
      q[k * 4 + j] = (signed char)__float2int_rn(t);
    }
  }
  *(int4*)(xq + (size_t)row * K_DIM + tid * 16) = *(const int4*)q;
}

__global__ __launch_bounds__(256) void cvt_w_i8(const float4* __restrict__ w,
                                                int4* __restrict__ wq) {
  const int i = blockIdx.x * blockDim.x + threadIdx.x;  // 16 floats / thread
  signed char q[16] __attribute__((aligned(16)));
#pragma unroll
  for (int k = 0; k < 4; ++k) {
    float4 v = w[i * 4 + k];
    q[k * 4 + 0] = sgn8(v.x);
    q[k * 4 + 1] = sgn8(v.y);
    q[k * 4 + 2] = sgn8(v.z);
    q[k * 4 + 3] = sgn8(v.w);
  }
  wq[i] = *(const int4*)q;
}

// ---------------- GEMM ----------------

// async global->LDS, 16 B/lane. LDS dest is the WAVE-UNIFORM base (HW adds lane*16);
// global src is per-lane (pre-swizzled so the linear LDS write lands swizzled).
__device__ __forceinline__ void load16_to_lds(const u8* g, const u8* l) {
  auto gp = reinterpret_cast<const __attribute__((address_space(1))) void*>(
      reinterpret_cast<uintptr_t>(g));
  auto lp = reinterpret_cast<__attribute__((address_space(3))) void*>(
      static_cast<uint32_t>(reinterpret_cast<uintptr_t>(l)));
  __builtin_amdgcn_global_load_lds(gp, lp, 16, 0, 0);
}

__device__ __forceinline__ i32x4 lds_read(const u8* base, int byteoff) {
  return *(const i32x4*)(base + byteoff);
}

// 256x256 8-phase i8 GEMM: C = s_row * (Xq (8192x4096 i8) * Wq^T (4096x4096 sign-i8)).
// Round-3 verified schedule with ONE sync edit: the trailing per-phase barrier
// (PH_END) is removed (setprio(0) kept). One barrier per phase (PH_MID) bounds
// wave skew to a single phase; ds_read/STAGE windows of phase p+1 now overlap
// MFMA of phase p across waves instead of strictly alternating.
// Race audit: all STAGE targets are disjoint from reads in the same and
// adjacent inter-barrier regions (round-3 ledger); gated reads are fenced by
// the vmcnt asm memory clobber + s_barrier; per-wave lgkmcnt(0) before MFMA.

#define PH_MID()                                           \
  __builtin_amdgcn_s_barrier();                            \
  asm volatile("s_waitcnt lgkmcnt(0)" ::: "memory");       \
  __builtin_amdgcn_s_setprio(1)

#define PH_END()                                           \
  __builtin_amdgcn_s_setprio(0)

#define STAGE(buf, mat, half, T)                                            \
  do {                                                                      \
    const u8* _s = ((mat) ? gBh[half] : gAh[half]) + (size_t)(T) * BKB;     \
    const u8* _r = &lds[buf][mat][half][0] + ldsw;                          \
    load16_to_lds(_s, _r);                                                  \
    load16_to_lds(_s + (size_t)64 * K_DIM, _r + 8192);                      \
  } while (0)

#define READ_A(buf, mbase)                                                  \
  _Pragma("unroll") for (int mi = 0; mi < 4; ++mi)                          \
  _Pragma("unroll") for (int kk = 0; kk < 2; ++kk)                          \
      af[mi][kk] = lds_read(Ab[buf], ((mbase) + mi) * 2048 + rowb + ck[kk])

#define READ_B0(buf)                                                        \
  _Pragma("unroll") for (int ni = 0; ni < 2; ++ni)                          \
  _Pragma("unroll") for (int kk = 0; kk < 2; ++kk)                          \
      b0f[ni][kk] = lds_read(Bb[buf], bofN + ni * 2048 + rowb + ck[kk])

#define READ_B1(buf)                                                        \
  _Pragma("unroll") for (int ni = 0; ni < 2; ++ni)                          \
  _Pragma("unroll") for (int kk = 0; kk < 2; ++kk)                          \
      b1f[ni][kk] = lds_read(Bb[buf], bofN + (ni + 2) * 2048 + rowb + ck[kk])

#define MFMA_Q(m0, n0, BF)                                                  \
  _Pragma("unroll") for (int kk = 0; kk < 2; ++kk)                          \
  _Pragma("unroll") for (int mi = 0; mi < 4; ++mi)                          \
  _Pragma("unroll") for (int ni = 0; ni < 2; ++ni)                          \
      acc[(m0) + mi][(n0) + ni] = __builtin_amdgcn_mfma_i32_16x16x64_i8(    \
          af[mi][kk], BF[ni][kk], acc[(m0) + mi][(n0) + ni], 0, 0, 0)

__global__ __launch_bounds__(512, 2) void bingemm_kernel(const u8* __restrict__ A,
                                                         const u8* __restrict__ B,
                                                         const float* __restrict__ S,
                                                         float* __restrict__ C) {
  __shared__ __align__(16) u8 lds[2][2][2][16384];  // 128 KiB

  const int tid = threadIdx.x;
  const int wave = tid >> 6;
  const int lane = tid & 63;

  // XCD-bijective swizzle (512 blocks % 8 XCDs == 0)
  const int orig = blockIdx.x;
  const int wgid = (orig & 7) * 64 + (orig >> 3);
  const int bm = wgid >> 4;  // 0..31
  const int bn = wgid & 15;  // 0..15

  const int wm = wave >> 2;  // wave's A half
  const int wn = wave & 3;   // wave's 64-col slice

  // ---- staging addresses (per-lane global src, pre-swizzled 16B chunk) ----
  const int l3 = lane >> 3;
  const int l7 = lane & 7;
  const int csw = (l7 ^ l3) << 4;  // swizzled chunk -> byte offset in 128B row
  const u8* gA = A + (size_t)(bm * 256 + wave * 8 + l3) * K_DIM + csw;
  const u8* gB = B + (size_t)(bn * 256 + wave * 8 + l3) * K_DIM + csw;
  const u8* gAh[2] = {gA, gA + (size_t)128 * K_DIM};
  const u8* gBh[2] = {gB, gB + (size_t)128 * K_DIM};
  const int ldsw = wave * 1024;  // wave-uniform byte offset within a region issue

  // ---- ds_read fragment addressing (swizzled) ----
  const int lane15 = lane & 15;
  const int lgrp = lane >> 4;
  const int rowb = lane15 * 128;  // byte row offset; row&7 == lane&7 for frag rows
  const int ck[2] = {((lgrp ^ l7) << 4), (((4 + lgrp) ^ l7) << 4)};
  const u8* Ab[2] = {&lds[0][0][wm][0], &lds[1][0][wm][0]};
  const u8* Bb[2] = {&lds[0][1][wn >> 1][0], &lds[1][1][wn >> 1][0]};
  const int bofN = (wn & 1) * 8192;  // byte offset of wave's 64-row slice in B region

  i32x4 acc[8][4];
  {
    const i32x4 z = {0, 0, 0, 0};
#pragma unroll
    for (int i = 0; i < 8; ++i)
#pragma unroll
      for (int j = 0; j < 4; ++j) acc[i][j] = z;
  }
  i32x4 af[4][2], b0f[2][2], b1f[2][2];

  // ---- prologue: T0 fully + T1's B halves; leave T1-B (4 loads) in flight ----
  STAGE(0, 1, 0, 0);
  STAGE(0, 1, 1, 0);
  STAGE(0, 0, 0, 0);
  STAGE(0, 0, 1, 0);
  STAGE(1, 1, 0, 1);
  STAGE(1, 1, 1, 1);
  asm volatile("s_waitcnt vmcnt(4)" ::: "memory");
  __builtin_amdgcn_s_barrier();

  for (int i = 0; i < NITER; ++i) {
    const int T1 = 2 * i + 1, T2 = 2 * i + 2, T3 = 2 * i + 3;
    const bool nl = (i < NITER - 1);

    // ph1: Q00(T0)
    READ_A(0, 0);
    READ_B0(0);
    STAGE(1, 0, 0, T1);
    PH_MID();
    MFMA_Q(0, 0, b0f);
    PH_END();

    // ph2: Q01(T0)
    READ_B1(0);
    STAGE(1, 0, 1, T1);
    PH_MID();
    MFMA_Q(0, 2, b1f);
    PH_END();

    // ph3: Q11(T0)
    READ_A(0, 4);
    if (nl) STAGE(0, 1, 0, T2);
    PH_MID();
    MFMA_Q(4, 2, b1f);
    PH_END();

    // ph4: Q10(T0) + gate (all of T1 landed before ph5 reads)
    if (nl) STAGE(0, 1, 1, T2);
    PH_MID();
    MFMA_Q(4, 0, b0f);
    __builtin_amdgcn_s_setprio(0);
    if (nl) asm volatile("s_waitcnt vmcnt(4)" ::: "memory");
    else    asm volatile("s_waitcnt vmcnt(0)" ::: "memory");
    __builtin_amdgcn_s_barrier();

    // ph5: Q00(T1)
    READ_A(1, 0);
    READ_B0(1);
    if (nl) STAGE(0, 0, 0, T2);
    PH_MID();
    MFMA_Q(0, 0, b0f);
    PH_END();

    // ph6: Q01(T1)
    READ_B1(1);
    if (nl) STAGE(0, 0, 1, T2);
    PH_MID();
    MFMA_Q(0, 2, b1f);
    PH_END();

    // ph7: Q11(T1)
    READ_A(1, 4);
    if (nl) STAGE(1, 1, 0, T3);
    PH_MID();
    MFMA_Q(4, 2, b1f);
    PH_END();

    // ph8: Q10(T1) + gate (all of T2 landed before next ph1 reads)
    if (nl) STAGE(1, 1, 1, T3);
    PH_MID();
    MFMA_Q(4, 0, b0f);
    __builtin_amdgcn_s_setprio(0);
    if (nl) asm volatile("s_waitcnt vmcnt(4)" ::: "memory");
    else    asm volatile("s_waitcnt vmcnt(0)" ::: "memory");
    __builtin_amdgcn_s_barrier();
  }

  // ---- epilogue: C/D layout col=lane&15, row=(lane>>4)*4+reg; dequant ----
  const int ccol = bn * 256 + wn * 64 + lane15;
  const int crow0 = bm * 256 + wm * 128 + (lgrp << 2);
#pragma unroll
  for (int mi = 0; mi < 8; ++mi) {
#pragma unroll
    for (int j = 0; j < 4; ++j) {
      const int row = crow0 + mi * 16 + j;
      const float s = S[row];
      float* cp = C + (size_t)row * N_DIM + ccol;
#pragma unroll
      for (int ni = 0; ni < 4; ++ni) cp[ni * 16] = s * (float)acc[mi][ni][j];
    }
  }
}

// Correctness fallback if d_ws is too small for the i8 staging buffers.
__global__ __launch_bounds__(256) void fallback_kernel(const float* __restrict__ x,
                                                       const float* __restrict__ w,
                                                       float* __restrict__ out) {
  const int col = blockIdx.x * 256 + threadIdx.x;
  const int row = blockIdx.y;
  const float* xr = x + (size_t)row * K_DIM;
  const float* wr = w + (size_t)col * K_DIM;
  float acc = 0.0f;
  for (int k = 0; k < K_DIM; k += 4) {
    float4 xv = *(const float4*)&xr[k];
    float4 wv = *(const float4*)&wr[k];
    acc += (wv.x > 0.0f ? xv.x : (wv.x < 0.0f ? -xv.x : 0.0f));
    acc += (wv.y > 0.0f ? xv.y : (wv.y < 0.0f ? -xv.y : 0.0f));
    acc += (wv.z > 0.0f ? xv.z : (wv.z < 0.0f ? -xv.z : 0.0f));
    acc += (wv.w > 0.0f ? xv.w : (wv.w < 0.0f ? -xv.w : 0.0f));
  }
  out[(size_t)row * N_DIM + col] = acc;
}

extern "C" void kernel_launch(void* const* d_in, const int* in_sizes, int n_in,
                              void* d_out, int out_size, void* d_ws, size_t ws_size,
                              hipStream_t stream) {
  const float* x = (const float*)d_in[0];  // (8192, 4096) fp32
  const float* w = (const float*)d_in[1];  // (4096, 4096) fp32
  float* out = (float*)d_out;              // (8192, 4096) fp32

  const size_t x_elems = (size_t)M_DIM * K_DIM;
  const size_t w_elems = (size_t)N_DIM * K_DIM;
  const size_t need = x_elems + w_elems + (size_t)M_DIM * sizeof(float);

  if (ws_size < need) {
    dim3 fgrid(N_DIM / 256, M_DIM);
    fallback_kernel<<<fgrid, 256, 0, stream>>>(x, w, out);
    return;
  }

  signed char* xq = (signed char*)d_ws;    // 32 MiB
  signed char* wq = xq + x_elems;          // 16 MiB
  float* scales = (float*)(wq + w_elems);  // 32 KiB

  cvt_x_i8<<<M_DIM, 256, 0, stream>>>(x, xq, scales);
  cvt_w_i8<<<(int)(w_elems / 16 / 256), 256, 0, stream>>>((const float4*)w, (int4*)wq);

  bingemm_kernel<<<(M_DIM / BM) * (N_DIM / BN), 512, 0, stream>>>(
      (const u8*)xq, (const u8*)wq, scales, out);
}